// Round 1
// baseline (1467.173 us; speedup 1.0000x reference)
//
#include <hip/hip_runtime.h>

#define SDIM 48
#define SP   (48*48*48)       // 110592
#define C_IN 16
#define O_OUT 32
#define T27  27
#define G81  81
#define KTOT 432              // C_IN * 27

// ---------------- Kernel 1: offset conv3d (K=3, pad=1, stride=1) -------------
// grid.x = 216 spatial blocks (2*48*48*12 work items / 256), grid.y = 3 g-passes
// Each thread: 4 consecutive x positions, 27 g-channels -> acc[27][4].
__global__ __launch_bounds__(256, 2)
void offs_conv_kernel(const float* __restrict__ x,
                      const float* __restrict__ ow,
                      const float* __restrict__ ob,
                      float* __restrict__ offs) {
    // weights for this pass: [k=432][g=27] padded to 28 for b128-friendly merging
    __shared__ float wlds[KTOT * 28];
    const int tid   = threadIdx.x;
    const int gbase = blockIdx.y * 27;

    for (int i = tid; i < 27 * KTOT; i += 256) {
        int gi = i / KTOT;
        int k  = i - gi * KTOT;
        wlds[k * 28 + gi] = ow[(gbase + gi) * KTOT + k];
    }
    __syncthreads();

    int wid = blockIdx.x * 256 + tid;           // 0 .. 55295
    int xg  = wid % 12;                          // x-group (4 x's each)
    int t1  = wid / 12;
    int y   = t1 % SDIM;
    int t2  = t1 / SDIM;
    int z   = t2 % SDIM;
    int n   = t2 / SDIM;

    float acc[27][4];
    #pragma unroll
    for (int gi = 0; gi < 27; ++gi)
        #pragma unroll
        for (int j = 0; j < 4; ++j) acc[gi][j] = 0.f;

    const int xb = xg * 4 - 1;
    for (int c = 0; c < C_IN; ++c) {
        for (int kz = 0; kz < 3; ++kz) {
            int zi = z + kz - 1;
            bool zok = (unsigned)zi < SDIM;
            for (int ky = 0; ky < 3; ++ky) {
                int yi = y + ky - 1;
                bool rowok = zok && ((unsigned)yi < SDIM);
                const float* rowp = x + ((((n * C_IN + c) * SDIM + zi) * SDIM + yi) * SDIM);
                float row[6];
                #pragma unroll
                for (int j = 0; j < 6; ++j) {
                    int xi = xb + j;
                    row[j] = (rowok && ((unsigned)xi < SDIM)) ? rowp[xi] : 0.f;
                }
                const int kbase = (c * 9 + kz * 3 + ky) * 3;
                #pragma unroll
                for (int kx = 0; kx < 3; ++kx) {
                    const float* wp = &wlds[(kbase + kx) * 28];
                    #pragma unroll
                    for (int gi = 0; gi < 27; ++gi) {
                        float wv = wp[gi];
                        #pragma unroll
                        for (int j = 0; j < 4; ++j)
                            acc[gi][j] = fmaf(wv, row[kx + j], acc[gi][j]);
                    }
                }
            }
        }
    }

    // store (+bias). 16B-aligned float4 stores.
    const int spbase = (z * SDIM + y) * SDIM + xg * 4;
    #pragma unroll
    for (int gi = 0; gi < 27; ++gi) {
        int g = gbase + gi;
        float b = ob[g];
        float4 v = make_float4(acc[gi][0] + b, acc[gi][1] + b,
                               acc[gi][2] + b, acc[gi][3] + b);
        *(float4*)(offs + (size_t)(n * G81 + g) * SP + spbase) = v;
    }
}

// ---------------- Kernel 2: deformable sampling + einsum ---------------------
// One thread per output spatial point; 32 output-channel accumulators.
__global__ __launch_bounds__(256, 2)
void deform_kernel(const float* __restrict__ x,
                   const float* __restrict__ w,     // [32][16][27]
                   const float* __restrict__ offs,  // [n][81][48][48][48]
                   float* __restrict__ out) {
    // einsum weights staged as [c][t][o] so the o-loop is 32 contiguous floats
    __shared__ float wl[C_IN * T27 * O_OUT];   // 13824 floats = 55.3 KB
    const int tid = threadIdx.x;
    for (int i = tid; i < C_IN * T27 * O_OUT; i += 256) {
        int o = i / (C_IN * T27);
        int r = i - o * (C_IN * T27);          // c*27 + t
        wl[r * O_OUT + o] = w[i];
    }
    __syncthreads();

    int wid = blockIdx.x * 256 + tid;          // 0 .. 221183
    int xq = wid % SDIM;
    int t1 = wid / SDIM;
    int y  = t1 % SDIM;
    int t2 = t1 / SDIM;
    int z  = t2 % SDIM;
    int n  = t2 / SDIM;

    float acc[32];
    #pragma unroll
    for (int o = 0; o < 32; ++o) acc[o] = 0.f;

    const int sp = (z * SDIM + y) * SDIM + xq;
    const float* offn = offs + (size_t)n * G81 * SP;
    const float* xn   = x + (size_t)n * C_IN * SP;

    for (int t = 0; t < T27; ++t) {
        int kd = t / 9, kh = (t / 3) % 3, kw = t % 3;
        float pd = (float)(z + kd - 1) + offn[(size_t)t        * SP + sp];
        float ph = (float)(y + kh - 1) + offn[(size_t)(27 + t) * SP + sp];
        float pw = (float)(xq + kw - 1) + offn[(size_t)(54 + t) * SP + sp];

        float d0f = floorf(pd), h0f = floorf(ph), w0f = floorf(pw);
        float fd = pd - d0f, fh = ph - h0f, fw = pw - w0f;
        int d0 = (int)d0f, h0 = (int)h0f, w0 = (int)w0f;

        float cw[8];
        int   coff[8];
        #pragma unroll
        for (int jj = 0; jj < 8; ++jj) {
            int dd = jj >> 2, hh = (jj >> 1) & 1, ww = jj & 1;
            int di = d0 + dd, hi = h0 + hh, wi = w0 + ww;
            bool ok = ((unsigned)di < SDIM) & ((unsigned)hi < SDIM) & ((unsigned)wi < SDIM);
            float wgt = (dd ? fd : 1.f - fd) * (hh ? fh : 1.f - fh) * (ww ? fw : 1.f - fw);
            cw[jj] = ok ? wgt : 0.f;
            int dc = min(max(di, 0), SDIM - 1);
            int hc = min(max(hi, 0), SDIM - 1);
            int wc = min(max(wi, 0), SDIM - 1);
            coff[jj] = (dc * SDIM + hc) * SDIM + wc;
        }

        for (int c = 0; c < C_IN; ++c) {
            const float* xc = xn + (size_t)c * SP;
            float s = 0.f;
            #pragma unroll
            for (int jj = 0; jj < 8; ++jj)
                s = fmaf(cw[jj], xc[coff[jj]], s);
            const float* wrow = &wl[(c * T27 + t) * O_OUT];
            #pragma unroll
            for (int o = 0; o < 32; ++o)
                acc[o] = fmaf(wrow[o], s, acc[o]);
        }
    }

    float* op = out + (size_t)n * O_OUT * SP + sp;
    #pragma unroll
    for (int o = 0; o < 32; ++o)
        op[(size_t)o * SP] = acc[o];
}

// -----------------------------------------------------------------------------
extern "C" void kernel_launch(void* const* d_in, const int* in_sizes, int n_in,
                              void* d_out, int out_size, void* d_ws, size_t ws_size,
                              hipStream_t stream) {
    const float* x      = (const float*)d_in[0];
    const float* weight = (const float*)d_in[1];
    const float* ow     = (const float*)d_in[2];
    const float* ob     = (const float*)d_in[3];
    float* out  = (float*)d_out;
    float* offs = (float*)d_ws;   // needs 2*81*110592*4 = 71.7 MB

    // Kernel 1: 2*48*48*12 = 55296 work items / 256 = 216 blocks, 3 g-passes
    offs_conv_kernel<<<dim3(216, 3), 256, 0, stream>>>(x, ow, ob, offs);
    // Kernel 2: 221184 points / 256 = 864 blocks
    deform_kernel<<<864, 256, 0, stream>>>(x, weight, offs, out);
}

// Round 2
// 330.256 us; speedup vs baseline: 4.4425x; 4.4425x over previous
//
#include <hip/hip_runtime.h>
#include <hip/hip_bf16.h>

#define SDIM 48
#define SP   110592           // 48^3
#define C_IN 16
#define O_OUT 32
#define T27  27
#define G81  81

typedef __attribute__((ext_vector_type(8))) short bf16x8;
typedef __attribute__((ext_vector_type(4))) float f32x4;

__device__ __forceinline__ float bf2f(unsigned short u) {
    unsigned int x = ((unsigned int)u) << 16;
    return __builtin_bit_cast(float, x);
}
__device__ __forceinline__ unsigned short f2bf(float f) {
    unsigned int x = __builtin_bit_cast(unsigned int, f);
    x += 0x7fffu + ((x >> 16) & 1u);     // RNE
    return (unsigned short)(x >> 16);
}

// ---------- Kernel 0a: x [n][c][sp] fp32 -> xT [n][sp][c] bf16 ---------------
__global__ __launch_bounds__(256)
void prep_xT(const float* __restrict__ x, unsigned short* __restrict__ xT) {
    __shared__ float l[256 * 17];
    const int tid = threadIdx.x;
    const int b   = blockIdx.x;          // 0..863
    const int n   = b / 432;
    const int sp0 = (b - n * 432) * 256;
    #pragma unroll
    for (int c = 0; c < 16; ++c)
        l[tid * 17 + c] = x[((size_t)(n * 16 + c)) * SP + sp0 + tid];
    __syncthreads();
    unsigned int u[8];
    #pragma unroll
    for (int q = 0; q < 8; ++q) {
        unsigned short a = f2bf(l[tid * 17 + 2 * q]);
        unsigned short bb = f2bf(l[tid * 17 + 2 * q + 1]);
        u[q] = (unsigned int)a | ((unsigned int)bb << 16);
    }
    uint4* dst = (uint4*)(xT + ((size_t)(n * SP + sp0 + tid)) * 16);
    dst[0] = make_uint4(u[0], u[1], u[2], u[3]);
    dst[1] = make_uint4(u[4], u[5], u[6], u[7]);
}

// ---------- Kernel 0b: pack conv weights into B-fragment layout --------------
// Bf[((s*6+nt)*64 + lane)*8 + r]; kk=(lane>>4)*8+r; g=nt*16+(lane&15);
// tap=2s+(kk>>4); c=kk&15; value = ow[g][c][tap] (0 if tap>=27 or g>=81)
__global__ __launch_bounds__(256)
void prep_bfrag(const float* __restrict__ ow, unsigned short* __restrict__ Bf) {
    int idx = blockIdx.x * 256 + threadIdx.x;     // 0..43007
    int r    = idx & 7;
    int lane = (idx >> 3) & 63;
    int snt  = idx >> 9;                          // s*6+nt, 0..83
    int s = snt / 6, nt = snt - s * 6;
    int kk  = ((lane >> 4) << 3) + r;
    int g   = nt * 16 + (lane & 15);
    int tap = 2 * s + (kk >> 4);
    int c   = kk & 15;
    float v = 0.f;
    if (tap < 27 && g < 81) v = ow[((size_t)(g * 16 + c)) * 27 + tap];
    Bf[idx] = f2bf(v);
}

// ---------- Kernel 1: offset conv as implicit-GEMM MFMA ----------------------
// M-tile 64 (4 waves x 16 rows), N = 96 (6 MFMA n-tiles, 81 real), K = 448
// (14 steps of 32 = 2 taps x 16 c). Output bf16 offs[n][g][sp].
__global__ __launch_bounds__(256)
void offs_conv_mfma(const unsigned short* __restrict__ xT,
                    const unsigned short* __restrict__ Bf,
                    const float* __restrict__ ob,
                    unsigned short* __restrict__ offs) {
    __shared__ unsigned short Alds[256 * 8];      // 4KB: chunk (j,m) at tid*16B
    const int tid  = threadIdx.x;
    const int lane = tid & 63;
    const int wid  = tid >> 6;
    const int j    = wid;                         // staging chunk group 0..3
    const int m    = tid & 63;
    const int gm   = blockIdx.x * 64 + m;
    const int n    = (gm >= SP) ? 1 : 0;
    const int sp   = gm - n * SP;
    const int z    = sp / 2304;
    const int rem  = sp - z * 2304;
    const int y    = rem / 48;
    const int xx   = rem - y * 48;
    const int tapoff = j >> 1;
    const int half   = j & 1;

    auto stage_load = [&](int s) -> uint4 {
        int tap = 2 * s + tapoff;
        int kd = tap / 9;
        int t2 = tap - kd * 9;
        int kh = t2 / 3;
        int kw = t2 - kh * 3;
        int di = z + kd - 1, hi = y + kh - 1, wi = xx + kw - 1;
        bool ok = (tap < 27) && ((unsigned)di < 48u) && ((unsigned)hi < 48u) &&
                  ((unsigned)wi < 48u);
        uint4 v = make_uint4(0u, 0u, 0u, 0u);
        if (ok) {
            size_t off = ((size_t)(n * SP + (di * 2304 + hi * 48 + wi))) * 16 + half * 8;
            v = *(const uint4*)(xT + off);
        }
        return v;
    };

    f32x4 acc[6];
    #pragma unroll
    for (int t = 0; t < 6; ++t) acc[t] = (f32x4){0.f, 0.f, 0.f, 0.f};

    uint4 v = stage_load(0);
    for (int s = 0; s < 14; ++s) {
        __syncthreads();
        *(uint4*)&Alds[tid * 8] = v;
        __syncthreads();
        if (s < 13) v = stage_load(s + 1);        // prefetch overlaps MFMA
        bf16x8 a = *(const bf16x8*)&Alds[(((lane >> 4) * 64) + (wid * 16) + (lane & 15)) * 8];
        const bf16x8* bp = (const bf16x8*)Bf + (size_t)(s * 6) * 64 + lane;
        #pragma unroll
        for (int nt = 0; nt < 6; ++nt) {
            bf16x8 b = bp[nt * 64];
            acc[nt] = __builtin_amdgcn_mfma_f32_16x16x32_bf16(a, b, acc[nt], 0, 0, 0);
        }
    }

    // epilogue: C/D layout col=lane&15 (g), row=(lane>>4)*4+reg (m)
    const int mrow = wid * 16 + ((lane >> 4) << 2);
    const int gmr  = blockIdx.x * 64 + mrow;
    const int n2   = (gmr >= SP) ? 1 : 0;
    const int spr  = gmr - n2 * SP;
    #pragma unroll
    for (int nt = 0; nt < 6; ++nt) {
        int g = nt * 16 + (lane & 15);
        if (g < 81) {
            float bia = ob[g];
            unsigned short h0 = f2bf(acc[nt][0] + bia);
            unsigned short h1 = f2bf(acc[nt][1] + bia);
            unsigned short h2 = f2bf(acc[nt][2] + bia);
            unsigned short h3 = f2bf(acc[nt][3] + bia);
            uint2 pv;
            pv.x = (unsigned int)h0 | ((unsigned int)h1 << 16);
            pv.y = (unsigned int)h2 | ((unsigned int)h3 << 16);
            *(uint2*)(offs + ((size_t)(n2 * 81 + g)) * SP + spr) = pv;
        }
    }
}

// ---------- Kernel 2: deformable sampling + einsum ---------------------------
__global__ __launch_bounds__(256, 2)
void deform_kernel(const unsigned short* __restrict__ xT,
                   const float* __restrict__ w,       // [32][16][27] fp32
                   const unsigned short* __restrict__ offs,
                   float* __restrict__ out) {
    __shared__ float wl[C_IN * T27 * O_OUT];          // [c*27+t][o], 55.3 KB
    const int tid = threadIdx.x;
    for (int i = tid; i < C_IN * T27 * O_OUT; i += 256) {
        int o = i / 432;
        int r = i - o * 432;                          // c*27+t
        wl[r * 32 + o] = w[i];
    }
    __syncthreads();

    int wp = blockIdx.x * 256 + tid;                  // 0..221183
    int n  = (wp >= SP) ? 1 : 0;
    int sp = wp - n * SP;
    int z  = sp / 2304;
    int rm = sp - z * 2304;
    int y  = rm / 48;
    int xq = rm - y * 48;

    float acc[32];
    #pragma unroll
    for (int o = 0; o < 32; ++o) acc[o] = 0.f;

    const unsigned short* offn = offs + (size_t)n * 81 * SP + sp;
    const unsigned short* xb   = xT + (size_t)n * SP * 16;

    for (int t = 0; t < 27; ++t) {
        int kd = t / 9;
        int tr = t - kd * 9;
        int kh = tr / 3;
        int kw = tr - kh * 3;
        float pd = (float)(z + kd - 1)  + bf2f(offn[(size_t)t * SP]);
        float ph = (float)(y + kh - 1)  + bf2f(offn[(size_t)(27 + t) * SP]);
        float pw = (float)(xq + kw - 1) + bf2f(offn[(size_t)(54 + t) * SP]);

        float d0f = floorf(pd), h0f = floorf(ph), w0f = floorf(pw);
        float fd = pd - d0f, fh = ph - h0f, fw = pw - w0f;
        int d0 = (int)d0f, h0 = (int)h0f, w0 = (int)w0f;

        float samp[16];
        #pragma unroll
        for (int c = 0; c < 16; ++c) samp[c] = 0.f;

        #pragma unroll
        for (int jj = 0; jj < 8; ++jj) {
            int dd = jj >> 2, hh = (jj >> 1) & 1, ww = jj & 1;
            int di = d0 + dd, hi = h0 + hh, wi = w0 + ww;
            bool ok = ((unsigned)di < 48u) & ((unsigned)hi < 48u) & ((unsigned)wi < 48u);
            float wgt = (dd ? fd : 1.f - fd) * (hh ? fh : 1.f - fh) * (ww ? fw : 1.f - fw);
            wgt = ok ? wgt : 0.f;
            int dc = min(max(di, 0), 47);
            int hc = min(max(hi, 0), 47);
            int wc = min(max(wi, 0), 47);
            const uint4* p = (const uint4*)(xb + ((size_t)((dc * 48 + hc) * 48 + wc)) * 16);
            uint4 v0 = p[0];
            uint4 v1 = p[1];
            unsigned int uu0 = v0.x, uu1 = v0.y, uu2 = v0.z, uu3 = v0.w;
            unsigned int uu4 = v1.x, uu5 = v1.y, uu6 = v1.z, uu7 = v1.w;
            #define UNPK(q, uw) { \
                float lo = __builtin_bit_cast(float, (uw) << 16); \
                float hf = __builtin_bit_cast(float, (uw) & 0xffff0000u); \
                samp[2*(q)]   = fmaf(wgt, lo, samp[2*(q)]); \
                samp[2*(q)+1] = fmaf(wgt, hf, samp[2*(q)+1]); }
            UNPK(0, uu0) UNPK(1, uu1) UNPK(2, uu2) UNPK(3, uu3)
            UNPK(4, uu4) UNPK(5, uu5) UNPK(6, uu6) UNPK(7, uu7)
            #undef UNPK
        }

        #pragma unroll
        for (int c = 0; c < 16; ++c) {
            const float* wr = &wl[(c * 27 + t) * 32];
            float s = samp[c];
            #pragma unroll
            for (int o = 0; o < 32; ++o)
                acc[o] = fmaf(wr[o], s, acc[o]);
        }
    }

    float* op = out + (size_t)n * 32 * SP + sp;
    #pragma unroll
    for (int o = 0; o < 32; ++o)
        op[(size_t)o * SP] = acc[o];
}

// -----------------------------------------------------------------------------
extern "C" void kernel_launch(void* const* d_in, const int* in_sizes, int n_in,
                              void* d_out, int out_size, void* d_ws, size_t ws_size,
                              hipStream_t stream) {
    (void)in_sizes; (void)n_in; (void)out_size; (void)ws_size;
    const float* x      = (const float*)d_in[0];
    const float* weight = (const float*)d_in[1];
    const float* ow     = (const float*)d_in[2];
    const float* ob     = (const float*)d_in[3];
    float* out = (float*)d_out;

    unsigned short* offs_b = (unsigned short*)d_ws;            // 2*81*SP bf16 = 35.8MB
    unsigned short* xT     = offs_b + (size_t)2 * 81 * SP;     // 2*SP*16 bf16 = 7.1MB
    unsigned short* Bf     = xT + (size_t)2 * SP * 16;         // 43008 bf16 = 86KB

    prep_xT<<<864, 256, 0, stream>>>(x, xT);
    prep_bfrag<<<168, 256, 0, stream>>>(ow, Bf);
    offs_conv_mfma<<<3456, 256, 0, stream>>>(xT, Bf, ob, offs_b);
    deform_kernel<<<864, 256, 0, stream>>>(xT, weight, offs_b, out);
}

// Round 3
// 183.249 us; speedup vs baseline: 8.0065x; 1.8022x over previous
//
#include <hip/hip_runtime.h>
#include <hip/hip_bf16.h>

#define SDIM 48
#define SP   110592           // 48^3
#define C_IN 16
#define O_OUT 32
#define T27  27
#define G81  81

typedef __attribute__((ext_vector_type(8))) short bf16x8;
typedef __attribute__((ext_vector_type(4))) float f32x4;

__device__ __forceinline__ float bf2f(unsigned short u) {
    unsigned int x = ((unsigned int)u) << 16;
    return __builtin_bit_cast(float, x);
}
__device__ __forceinline__ unsigned short f2bf(float f) {
    unsigned int x = __builtin_bit_cast(unsigned int, f);
    x += 0x7fffu + ((x >> 16) & 1u);     // RNE
    return (unsigned short)(x >> 16);
}

// ---------- Kernel 0a: x [n][c][sp] fp32 -> xT [n][sp][c] bf16 ---------------
__global__ __launch_bounds__(256)
void prep_xT(const float* __restrict__ x, unsigned short* __restrict__ xT) {
    __shared__ float l[256 * 17];
    const int tid = threadIdx.x;
    const int b   = blockIdx.x;          // 0..863
    const int n   = b / 432;
    const int sp0 = (b - n * 432) * 256;
    #pragma unroll
    for (int c = 0; c < 16; ++c)
        l[tid * 17 + c] = x[((size_t)(n * 16 + c)) * SP + sp0 + tid];
    __syncthreads();
    unsigned int u[8];
    #pragma unroll
    for (int q = 0; q < 8; ++q) {
        unsigned short a = f2bf(l[tid * 17 + 2 * q]);
        unsigned short bb = f2bf(l[tid * 17 + 2 * q + 1]);
        u[q] = (unsigned int)a | ((unsigned int)bb << 16);
    }
    uint4* dst = (uint4*)(xT + ((size_t)(n * SP + sp0 + tid)) * 16);
    dst[0] = make_uint4(u[0], u[1], u[2], u[3]);
    dst[1] = make_uint4(u[4], u[5], u[6], u[7]);
}

// ---------- Kernel 0b: pack offset-conv weights into B-fragment layout -------
// Bf[((s*6+nt)*64 + lane)*8 + r]; kk=(lane>>4)*8+r; g=nt*16+(lane&15);
// tap=2s+(kk>>4); c=kk&15; value = ow[g][c][tap] (0 if tap>=27 or g>=81)
__global__ __launch_bounds__(256)
void prep_bfrag(const float* __restrict__ ow, unsigned short* __restrict__ Bf) {
    int idx = blockIdx.x * 256 + threadIdx.x;     // 0..43007
    int r    = idx & 7;
    int lane = (idx >> 3) & 63;
    int snt  = idx >> 9;                          // s*6+nt, 0..83
    int s = snt / 6, nt = snt - s * 6;
    int kk  = ((lane >> 4) << 3) + r;
    int g   = nt * 16 + (lane & 15);
    int tap = 2 * s + (kk >> 4);
    int c   = kk & 15;
    float v = 0.f;
    if (tap < 27 && g < 81) v = ow[((size_t)(g * 16 + c)) * 27 + tap];
    Bf[idx] = f2bf(v);
}

// ---------- Kernel 0c: pack einsum weights [32][16][27] into B-frag layout ---
// Wf[((s*2+nt)*64 + lane)*8 + r]; kk=(lane>>4)*8+r; o=nt*16+(lane&15);
// tap=2s+(kk>>4); c=kk&15; value = w[o][c][tap] (0 if tap>=27)
__global__ __launch_bounds__(256)
void prep_wfrag(const float* __restrict__ w, unsigned short* __restrict__ Wf) {
    int idx = blockIdx.x * 256 + threadIdx.x;     // 0..14335
    int r    = idx & 7;
    int lane = (idx >> 3) & 63;
    int snt  = idx >> 9;                          // s*2+nt, 0..27
    int s = snt >> 1, nt = snt & 1;
    int kk  = ((lane >> 4) << 3) + r;
    int o   = nt * 16 + (lane & 15);
    int tap = 2 * s + (kk >> 4);
    int c   = kk & 15;
    float v = 0.f;
    if (tap < 27) v = w[((size_t)(o * 16 + c)) * 27 + tap];
    Wf[idx] = f2bf(v);
}

// ---------- Kernel 1: offset conv as implicit-GEMM MFMA ----------------------
__global__ __launch_bounds__(256)
void offs_conv_mfma(const unsigned short* __restrict__ xT,
                    const unsigned short* __restrict__ Bf,
                    const float* __restrict__ ob,
                    unsigned short* __restrict__ offs) {
    __shared__ unsigned short Alds[256 * 8];      // 4KB
    const int tid  = threadIdx.x;
    const int lane = tid & 63;
    const int wid  = tid >> 6;
    const int j    = wid;
    const int m    = tid & 63;
    const int gm   = blockIdx.x * 64 + m;
    const int n    = (gm >= SP) ? 1 : 0;
    const int sp   = gm - n * SP;
    const int z    = sp / 2304;
    const int rem  = sp - z * 2304;
    const int y    = rem / 48;
    const int xx   = rem - y * 48;
    const int tapoff = j >> 1;
    const int half   = j & 1;

    auto stage_load = [&](int s) -> uint4 {
        int tap = 2 * s + tapoff;
        int kd = tap / 9;
        int t2 = tap - kd * 9;
        int kh = t2 / 3;
        int kw = t2 - kh * 3;
        int di = z + kd - 1, hi = y + kh - 1, wi = xx + kw - 1;
        bool ok = (tap < 27) && ((unsigned)di < 48u) && ((unsigned)hi < 48u) &&
                  ((unsigned)wi < 48u);
        uint4 v = make_uint4(0u, 0u, 0u, 0u);
        if (ok) {
            size_t off = ((size_t)(n * SP + (di * 2304 + hi * 48 + wi))) * 16 + half * 8;
            v = *(const uint4*)(xT + off);
        }
        return v;
    };

    f32x4 acc[6];
    #pragma unroll
    for (int t = 0; t < 6; ++t) acc[t] = (f32x4){0.f, 0.f, 0.f, 0.f};

    uint4 v = stage_load(0);
    for (int s = 0; s < 14; ++s) {
        __syncthreads();
        *(uint4*)&Alds[tid * 8] = v;
        __syncthreads();
        if (s < 13) v = stage_load(s + 1);        // prefetch overlaps MFMA
        bf16x8 a = *(const bf16x8*)&Alds[(((lane >> 4) * 64) + (wid * 16) + (lane & 15)) * 8];
        const bf16x8* bp = (const bf16x8*)Bf + (size_t)(s * 6) * 64 + lane;
        #pragma unroll
        for (int nt = 0; nt < 6; ++nt) {
            bf16x8 b = bp[nt * 64];
            acc[nt] = __builtin_amdgcn_mfma_f32_16x16x32_bf16(a, b, acc[nt], 0, 0, 0);
        }
    }

    const int mrow = wid * 16 + ((lane >> 4) << 2);
    const int gmr  = blockIdx.x * 64 + mrow;
    const int n2   = (gmr >= SP) ? 1 : 0;
    const int spr  = gmr - n2 * SP;
    #pragma unroll
    for (int nt = 0; nt < 6; ++nt) {
        int g = nt * 16 + (lane & 15);
        if (g < 81) {
            float bia = ob[g];
            unsigned short h0 = f2bf(acc[nt][0] + bia);
            unsigned short h1 = f2bf(acc[nt][1] + bia);
            unsigned short h2 = f2bf(acc[nt][2] + bia);
            unsigned short h3 = f2bf(acc[nt][3] + bia);
            uint2 pv;
            pv.x = (unsigned int)h0 | ((unsigned int)h1 << 16);
            pv.y = (unsigned int)h2 | ((unsigned int)h3 << 16);
            *(uint2*)(offs + ((size_t)(n2 * 81 + g)) * SP + spr) = pv;
        }
    }
}

// ---------- Kernel 2: fused trilinear sampling + MFMA einsum -----------------
// 64-point m-tile, K = 448 (14 steps x 32 = 2 taps x 16 ch). Wave j stages
// (tap = 2s + (j>>1), channels (j&1)*8..+7) for all 64 points of the tile.
__global__ __launch_bounds__(256, 4)
void deform_mfma(const unsigned short* __restrict__ xT,
                 const unsigned short* __restrict__ Wf,
                 const unsigned short* __restrict__ offs,
                 float* __restrict__ out) {
    __shared__ unsigned short Alds[256 * 8];      // 4 KB
    __shared__ float olds[32 * 65];               // 8.3 KB, stride 65 anti-conflict
    const int tid  = threadIdx.x;
    const int lane = tid & 63;
    const int wid  = tid >> 6;
    const int j    = wid;
    const int m    = lane;
    const int n    = (blockIdx.x >= 1728) ? 1 : 0;   // SP%64==0: no n-crossing
    const int sp0  = blockIdx.x * 64 - n * SP;
    const int sp   = sp0 + m;
    const int z    = sp / 2304;
    const int rm   = sp - z * 2304;
    const int y    = rm / 48;
    const int xx   = rm - y * 48;
    const int tapoff = j >> 1;
    const int half   = j & 1;

    const unsigned short* offn = offs + (size_t)n * G81 * SP + sp;
    const unsigned short* xb   = xT + (size_t)n * SP * 16;

    auto stage = [&](int s) -> uint4 {
        int tap = 2 * s + tapoff;
        uint4 res = make_uint4(0u, 0u, 0u, 0u);
        if (tap < 27) {
            int kd = tap / 9;
            int t2 = tap - kd * 9;
            int kh = t2 / 3;
            int kw = t2 - kh * 3;
            float pd = (float)(z + kd - 1)  + bf2f(offn[(size_t)tap * SP]);
            float ph = (float)(y + kh - 1)  + bf2f(offn[(size_t)(27 + tap) * SP]);
            float pw = (float)(xx + kw - 1) + bf2f(offn[(size_t)(54 + tap) * SP]);
            float d0f = floorf(pd), h0f = floorf(ph), w0f = floorf(pw);
            float fd = pd - d0f, fh = ph - h0f, fw = pw - w0f;
            int d0 = (int)d0f, h0 = (int)h0f, w0 = (int)w0f;

            float cw[8];
            const uint4* cp[8];
            #pragma unroll
            for (int jj = 0; jj < 8; ++jj) {
                int dd = jj >> 2, hh = (jj >> 1) & 1, ww = jj & 1;
                int di = d0 + dd, hi = h0 + hh, wi = w0 + ww;
                bool ok = ((unsigned)di < 48u) & ((unsigned)hi < 48u) & ((unsigned)wi < 48u);
                float wgt = (dd ? fd : 1.f - fd) * (hh ? fh : 1.f - fh) * (ww ? fw : 1.f - fw);
                cw[jj] = ok ? wgt : 0.f;
                int dc = min(max(di, 0), 47);
                int hc = min(max(hi, 0), 47);
                int wc = min(max(wi, 0), 47);
                cp[jj] = (const uint4*)(xb + ((size_t)((dc * 48 + hc) * 48 + wc)) * 16 + half * 8);
            }
            uint4 cv[8];
            #pragma unroll
            for (int jj = 0; jj < 8; ++jj) cv[jj] = *cp[jj];

            float sm[8];
            #pragma unroll
            for (int q = 0; q < 8; ++q) sm[q] = 0.f;
            #pragma unroll
            for (int jj = 0; jj < 8; ++jj) {
                float wgt = cw[jj];
                unsigned int uu[4] = {cv[jj].x, cv[jj].y, cv[jj].z, cv[jj].w};
                #pragma unroll
                for (int q = 0; q < 4; ++q) {
                    float lo = __builtin_bit_cast(float, uu[q] << 16);
                    float hf = __builtin_bit_cast(float, uu[q] & 0xffff0000u);
                    sm[2 * q]     = fmaf(wgt, lo, sm[2 * q]);
                    sm[2 * q + 1] = fmaf(wgt, hf, sm[2 * q + 1]);
                }
            }
            res.x = (unsigned int)f2bf(sm[0]) | ((unsigned int)f2bf(sm[1]) << 16);
            res.y = (unsigned int)f2bf(sm[2]) | ((unsigned int)f2bf(sm[3]) << 16);
            res.z = (unsigned int)f2bf(sm[4]) | ((unsigned int)f2bf(sm[5]) << 16);
            res.w = (unsigned int)f2bf(sm[6]) | ((unsigned int)f2bf(sm[7]) << 16);
        }
        return res;
    };

    f32x4 acc[2];
    acc[0] = (f32x4){0.f, 0.f, 0.f, 0.f};
    acc[1] = (f32x4){0.f, 0.f, 0.f, 0.f};

    uint4 v = stage(0);
    for (int s = 0; s < 14; ++s) {
        __syncthreads();
        *(uint4*)&Alds[tid * 8] = v;
        __syncthreads();
        if (s < 13) v = stage(s + 1);             // heavy sampling overlaps MFMA
        bf16x8 a = *(const bf16x8*)&Alds[(((lane >> 4) * 64) + (wid * 16) + (lane & 15)) * 8];
        const bf16x8* bp = (const bf16x8*)Wf + (size_t)(s * 2) * 64 + lane;
        acc[0] = __builtin_amdgcn_mfma_f32_16x16x32_bf16(a, bp[0],  acc[0], 0, 0, 0);
        acc[1] = __builtin_amdgcn_mfma_f32_16x16x32_bf16(a, bp[64], acc[1], 0, 0, 0);
    }

    // epilogue: transpose through LDS -> coalesced plane-major float4 stores
    __syncthreads();
    const int mr = wid * 16 + ((lane >> 4) << 2);
    #pragma unroll
    for (int nt = 0; nt < 2; ++nt) {
        int o = nt * 16 + (lane & 15);
        #pragma unroll
        for (int r = 0; r < 4; ++r)
            olds[o * 65 + mr + r] = acc[nt][r];
    }
    __syncthreads();
    const int o  = tid >> 3;
    const int m8 = (tid & 7) * 8;
    float* op = out + ((size_t)(n * O_OUT + o)) * SP + sp0 + m8;
    float4 a0 = make_float4(olds[o * 65 + m8],     olds[o * 65 + m8 + 1],
                            olds[o * 65 + m8 + 2], olds[o * 65 + m8 + 3]);
    float4 a1 = make_float4(olds[o * 65 + m8 + 4], olds[o * 65 + m8 + 5],
                            olds[o * 65 + m8 + 6], olds[o * 65 + m8 + 7]);
    *(float4*)op       = a0;
    *(float4*)(op + 4) = a1;
}

// -----------------------------------------------------------------------------
extern "C" void kernel_launch(void* const* d_in, const int* in_sizes, int n_in,
                              void* d_out, int out_size, void* d_ws, size_t ws_size,
                              hipStream_t stream) {
    (void)in_sizes; (void)n_in; (void)out_size; (void)ws_size;
    const float* x      = (const float*)d_in[0];
    const float* weight = (const float*)d_in[1];
    const float* ow     = (const float*)d_in[2];
    const float* ob     = (const float*)d_in[3];
    float* out = (float*)d_out;

    unsigned short* offs_b = (unsigned short*)d_ws;            // 2*81*SP bf16 = 35.8MB
    unsigned short* xT     = offs_b + (size_t)2 * 81 * SP;     // 2*SP*16 bf16 = 7.1MB
    unsigned short* Bf     = xT + (size_t)2 * SP * 16;         // 43008 bf16
    unsigned short* Wf     = Bf + 43008;                       // 14336 bf16

    prep_xT<<<864, 256, 0, stream>>>(x, xT);
    prep_bfrag<<<168, 256, 0, stream>>>(ow, Bf);
    prep_wfrag<<<56, 256, 0, stream>>>(weight, Wf);
    offs_conv_mfma<<<3456, 256, 0, stream>>>(xT, Bf, ob, offs_b);
    deform_mfma<<<3456, 256, 0, stream>>>(xT, Wf, offs_b, out);
}

// Round 4
// 171.844 us; speedup vs baseline: 8.5378x; 1.0664x over previous
//
#include <hip/hip_runtime.h>
#include <hip/hip_bf16.h>

#define SDIM 48
#define SP   110592           // 48^3
#define C_IN 16
#define O_OUT 32
#define T27  27
#define G81  81

typedef __attribute__((ext_vector_type(8))) short bf16x8;
typedef __attribute__((ext_vector_type(4))) float f32x4;
typedef __attribute__((ext_vector_type(2))) float f32x2;

__device__ __forceinline__ float bf2f(unsigned short u) {
    unsigned int x = ((unsigned int)u) << 16;
    return __builtin_bit_cast(float, x);
}
__device__ __forceinline__ unsigned short f2bf(float f) {
    unsigned int x = __builtin_bit_cast(unsigned int, f);
    x += 0x7fffu + ((x >> 16) & 1u);     // RNE
    return (unsigned short)(x >> 16);
}

// ---------- Kernel 0a: x [n][c][sp] fp32 -> xT [n][sp][c] bf16 ---------------
__global__ __launch_bounds__(256)
void prep_xT(const float* __restrict__ x, unsigned short* __restrict__ xT) {
    __shared__ float l[256 * 17];
    const int tid = threadIdx.x;
    const int b   = blockIdx.x;          // 0..863
    const int n   = b / 432;
    const int sp0 = (b - n * 432) * 256;
    #pragma unroll
    for (int c = 0; c < 16; ++c)
        l[tid * 17 + c] = x[((size_t)(n * 16 + c)) * SP + sp0 + tid];
    __syncthreads();
    unsigned int u[8];
    #pragma unroll
    for (int q = 0; q < 8; ++q) {
        unsigned short a = f2bf(l[tid * 17 + 2 * q]);
        unsigned short bb = f2bf(l[tid * 17 + 2 * q + 1]);
        u[q] = (unsigned int)a | ((unsigned int)bb << 16);
    }
    uint4* dst = (uint4*)(xT + ((size_t)(n * SP + sp0 + tid)) * 16);
    dst[0] = make_uint4(u[0], u[1], u[2], u[3]);
    dst[1] = make_uint4(u[4], u[5], u[6], u[7]);
}

// ---------- Kernel 0b: pack offset-conv weights into B-fragment layout -------
__global__ __launch_bounds__(256)
void prep_bfrag(const float* __restrict__ ow, unsigned short* __restrict__ Bf) {
    int idx = blockIdx.x * 256 + threadIdx.x;     // 0..43007
    int r    = idx & 7;
    int lane = (idx >> 3) & 63;
    int snt  = idx >> 9;                          // s*6+nt, 0..83
    int s = snt / 6, nt = snt - s * 6;
    int kk  = ((lane >> 4) << 3) + r;
    int g   = nt * 16 + (lane & 15);
    int tap = 2 * s + (kk >> 4);
    int c   = kk & 15;
    float v = 0.f;
    if (tap < 27 && g < 81) v = ow[((size_t)(g * 16 + c)) * 27 + tap];
    Bf[idx] = f2bf(v);
}

// ---------- Kernel 0c: pack einsum weights [32][16][27] into B-frag layout ---
__global__ __launch_bounds__(256)
void prep_wfrag(const float* __restrict__ w, unsigned short* __restrict__ Wf) {
    int idx = blockIdx.x * 256 + threadIdx.x;     // 0..14335
    int r    = idx & 7;
    int lane = (idx >> 3) & 63;
    int snt  = idx >> 9;                          // s*2+nt, 0..27
    int s = snt >> 1, nt = snt & 1;
    int kk  = ((lane >> 4) << 3) + r;
    int o   = nt * 16 + (lane & 15);
    int tap = 2 * s + (kk >> 4);
    int c   = kk & 15;
    float v = 0.f;
    if (tap < 27) v = w[((size_t)(o * 16 + c)) * 27 + tap];
    Wf[idx] = f2bf(v);
}

// ---------- Kernel 1: offset conv as implicit-GEMM MFMA ----------------------
__global__ __launch_bounds__(256)
void offs_conv_mfma(const unsigned short* __restrict__ xT,
                    const unsigned short* __restrict__ Bf,
                    const float* __restrict__ ob,
                    unsigned short* __restrict__ offs) {
    __shared__ unsigned short Alds[256 * 8];      // 4KB
    const int tid  = threadIdx.x;
    const int lane = tid & 63;
    const int wid  = tid >> 6;
    const int j    = wid;
    const int m    = tid & 63;
    const int gm   = blockIdx.x * 64 + m;
    const int n    = (gm >= SP) ? 1 : 0;
    const int sp   = gm - n * SP;
    const int z    = sp / 2304;
    const int rem  = sp - z * 2304;
    const int y    = rem / 48;
    const int xx   = rem - y * 48;
    const int tapoff = j >> 1;
    const int half   = j & 1;

    auto stage_load = [&](int s) -> uint4 {
        int tap = 2 * s + tapoff;
        int kd = tap / 9;
        int t2 = tap - kd * 9;
        int kh = t2 / 3;
        int kw = t2 - kh * 3;
        int di = z + kd - 1, hi = y + kh - 1, wi = xx + kw - 1;
        bool ok = (tap < 27) && ((unsigned)di < 48u) && ((unsigned)hi < 48u) &&
                  ((unsigned)wi < 48u);
        uint4 v = make_uint4(0u, 0u, 0u, 0u);
        if (ok) {
            size_t off = ((size_t)(n * SP + (di * 2304 + hi * 48 + wi))) * 16 + half * 8;
            v = *(const uint4*)(xT + off);
        }
        return v;
    };

    f32x4 acc[6];
    #pragma unroll
    for (int t = 0; t < 6; ++t) acc[t] = (f32x4){0.f, 0.f, 0.f, 0.f};

    uint4 v = stage_load(0);
    for (int s = 0; s < 14; ++s) {
        __syncthreads();
        *(uint4*)&Alds[tid * 8] = v;
        __syncthreads();
        if (s < 13) v = stage_load(s + 1);        // prefetch overlaps MFMA
        bf16x8 a = *(const bf16x8*)&Alds[(((lane >> 4) * 64) + (wid * 16) + (lane & 15)) * 8];
        const bf16x8* bp = (const bf16x8*)Bf + (size_t)(s * 6) * 64 + lane;
        #pragma unroll
        for (int nt = 0; nt < 6; ++nt) {
            bf16x8 b = bp[nt * 64];
            acc[nt] = __builtin_amdgcn_mfma_f32_16x16x32_bf16(a, b, acc[nt], 0, 0, 0);
        }
    }

    const int mrow = wid * 16 + ((lane >> 4) << 2);
    const int gmr  = blockIdx.x * 64 + mrow;
    const int n2   = (gmr >= SP) ? 1 : 0;
    const int spr  = gmr - n2 * SP;
    #pragma unroll
    for (int nt = 0; nt < 6; ++nt) {
        int g = nt * 16 + (lane & 15);
        if (g < 81) {
            float bia = ob[g];
            unsigned short h0 = f2bf(acc[nt][0] + bia);
            unsigned short h1 = f2bf(acc[nt][1] + bia);
            unsigned short h2 = f2bf(acc[nt][2] + bia);
            unsigned short h3 = f2bf(acc[nt][3] + bia);
            uint2 pv;
            pv.x = (unsigned int)h0 | ((unsigned int)h1 << 16);
            pv.y = (unsigned int)h2 | ((unsigned int)h3 << 16);
            *(uint2*)(offs + ((size_t)(n2 * 81 + g)) * SP + spr) = pv;
        }
    }
}

// ---------- Kernel 2: fused trilinear sampling + MFMA einsum -----------------
// One tap per thread per round: 4 taps x 64 points staged per LDS round,
// K = 64 per round (2 MFMA k-steps), 7 rounds = 28 taps (tap 27 zero).
__global__ __launch_bounds__(256, 4)
void deform_mfma(const unsigned short* __restrict__ xT,
                 const unsigned short* __restrict__ Wf,
                 const unsigned short* __restrict__ offs,
                 float* __restrict__ out) {
    __shared__ unsigned short Alds[4 * 64 * 24];  // [tap][point][16ch], 48B stride
    __shared__ float olds[32 * 65];               // epilogue transpose
    const int tid  = threadIdx.x;
    const int lane = tid & 63;
    const int wid  = tid >> 6;                    // tap slot 0..3
    const int m    = lane;                        // point within tile
    const int n    = (blockIdx.x >= 1728) ? 1 : 0;
    const int sp0  = blockIdx.x * 64 - n * SP;
    const int sp   = sp0 + m;
    const int z    = sp / 2304;
    const int rm   = sp - z * 2304;
    const int y    = rm / 48;
    const int xx   = rm - y * 48;

    const unsigned short* offn = offs + (size_t)n * G81 * SP + sp;
    const uint4* xq4 = (const uint4*)(xT + (size_t)n * SP * 16);

    struct Stg { uint4 a, b; };

    auto stage = [&](int rr) -> Stg {
        Stg res;
        res.a = make_uint4(0u, 0u, 0u, 0u);
        res.b = make_uint4(0u, 0u, 0u, 0u);
        const int tap = 4 * rr + wid;
        if (tap >= 27) return res;
        const int kd = tap / 9;
        const int t2 = tap - kd * 9;
        const int kh = t2 / 3;
        const int kw = t2 - kh * 3;
        float pd = (float)(z + kd - 1)  + bf2f(offn[(size_t)tap * SP]);
        float ph = (float)(y + kh - 1)  + bf2f(offn[(size_t)(27 + tap) * SP]);
        float pw = (float)(xx + kw - 1) + bf2f(offn[(size_t)(54 + tap) * SP]);
        float df = floorf(pd), hf = floorf(ph), wf = floorf(pw);
        float fd = pd - df, fh = ph - hf, fw = pw - wf;
        int d0 = (int)df, h0 = (int)hf, w0 = (int)wf;
        // validity folded into axis weights (corner weight = product -> 0 if any OOB)
        float wd0 = ((unsigned)d0       < 48u) ? (1.f - fd) : 0.f;
        float wd1 = ((unsigned)(d0 + 1) < 48u) ? fd : 0.f;
        float wh0 = ((unsigned)h0       < 48u) ? (1.f - fh) : 0.f;
        float wh1 = ((unsigned)(h0 + 1) < 48u) ? fh : 0.f;
        float ww0 = ((unsigned)w0       < 48u) ? (1.f - fw) : 0.f;
        float ww1 = ((unsigned)(w0 + 1) < 48u) ? fw : 0.f;
        // clamped per-axis index terms (weight==0 wherever clamp changes cell)
        int dc0 = min(max(d0,     0), 47) * 2304;
        int dc1 = min(max(d0 + 1, 0), 47) * 2304;
        int hc0 = min(max(h0,     0), 47) * 48;
        int hc1 = min(max(h0 + 1, 0), 47) * 48;
        int wc0 = min(max(w0,     0), 47);
        int wc1 = min(max(w0 + 1, 0), 47);

        float wdh[4] = {wd0 * wh0, wd0 * wh1, wd1 * wh0, wd1 * wh1};
        int   rdh[4] = {dc0 + hc0, dc0 + hc1, dc1 + hc0, dc1 + hc1};

        f32x2 s2v[8];
        #pragma unroll
        for (int q = 0; q < 8; ++q) s2v[q] = (f32x2){0.f, 0.f};

        #pragma unroll
        for (int g2 = 0; g2 < 2; ++g2) {          // 4 corners per batch
            uint4 cv[8];
            float cwt[4];
            #pragma unroll
            for (int pidx = 0; pidx < 2; ++pidx) {
                int jj = g2 * 2 + pidx;           // dh combo
                int i0 = rdh[jj] + wc0;
                int i1 = rdh[jj] + wc1;
                cv[pidx * 4 + 0] = xq4[(size_t)i0 * 2];
                cv[pidx * 4 + 1] = xq4[(size_t)i0 * 2 + 1];
                cv[pidx * 4 + 2] = xq4[(size_t)i1 * 2];
                cv[pidx * 4 + 3] = xq4[(size_t)i1 * 2 + 1];
                cwt[pidx * 2 + 0] = wdh[jj] * ww0;
                cwt[pidx * 2 + 1] = wdh[jj] * ww1;
            }
            #pragma unroll
            for (int pidx = 0; pidx < 2; ++pidx) {
                #pragma unroll
                for (int wsel = 0; wsel < 2; ++wsel) {
                    f32x2 w2;
                    w2.x = cwt[pidx * 2 + wsel];
                    w2.y = w2.x;
                    const uint4& lo4 = cv[pidx * 4 + wsel * 2];
                    const uint4& hi4 = cv[pidx * 4 + wsel * 2 + 1];
                    unsigned int wd_[8] = {lo4.x, lo4.y, lo4.z, lo4.w,
                                           hi4.x, hi4.y, hi4.z, hi4.w};
                    #pragma unroll
                    for (int q = 0; q < 8; ++q) {
                        f32x2 xv;
                        xv.x = __builtin_bit_cast(float, wd_[q] << 16);
                        xv.y = __builtin_bit_cast(float, wd_[q] & 0xffff0000u);
                        s2v[q] = __builtin_elementwise_fma(xv, w2, s2v[q]);
                    }
                }
            }
        }
        unsigned int o_[8];
        #pragma unroll
        for (int q = 0; q < 8; ++q) {
            unsigned int r_;
            asm("v_cvt_pk_bf16_f32 %0, %1, %2" : "=v"(r_) : "v"(s2v[q].x), "v"(s2v[q].y));
            o_[q] = r_;
        }
        res.a = make_uint4(o_[0], o_[1], o_[2], o_[3]);
        res.b = make_uint4(o_[4], o_[5], o_[6], o_[7]);
        return res;
    };

    f32x4 acc0 = (f32x4){0.f, 0.f, 0.f, 0.f};
    f32x4 acc1 = (f32x4){0.f, 0.f, 0.f, 0.f};

    const int q_   = lane >> 4;
    const int tl   = q_ >> 1;                     // tap-local within k-step
    const int chh  = q_ & 1;                      // channel half
    const int rowm = wid * 16 + (lane & 15);      // A-fragment row (point)

    Stg v = stage(0);
    for (int rr = 0; rr < 7; ++rr) {
        __syncthreads();
        unsigned short* wp_ = &Alds[(wid * 64 + m) * 24];
        *(uint4*)wp_ = v.a;
        *(uint4*)(wp_ + 8) = v.b;
        __syncthreads();
        if (rr < 6) v = stage(rr + 1);            // sampling overlaps MFMA
        bf16x8 a0 = *(const bf16x8*)&Alds[((tl * 64) + rowm) * 24 + chh * 8];
        bf16x8 a1 = *(const bf16x8*)&Alds[(((2 + tl) * 64) + rowm) * 24 + chh * 8];
        const bf16x8* bp0 = (const bf16x8*)Wf + (size_t)((2 * rr + 0) * 2) * 64 + lane;
        const bf16x8* bp1 = (const bf16x8*)Wf + (size_t)((2 * rr + 1) * 2) * 64 + lane;
        acc0 = __builtin_amdgcn_mfma_f32_16x16x32_bf16(a0, bp0[0],  acc0, 0, 0, 0);
        acc1 = __builtin_amdgcn_mfma_f32_16x16x32_bf16(a0, bp0[64], acc1, 0, 0, 0);
        acc0 = __builtin_amdgcn_mfma_f32_16x16x32_bf16(a1, bp1[0],  acc0, 0, 0, 0);
        acc1 = __builtin_amdgcn_mfma_f32_16x16x32_bf16(a1, bp1[64], acc1, 0, 0, 0);
    }

    // epilogue: transpose through LDS -> coalesced plane-major float4 stores
    __syncthreads();
    const int mr = wid * 16 + ((lane >> 4) << 2);
    {
        int o = lane & 15;
        #pragma unroll
        for (int r = 0; r < 4; ++r) olds[o * 65 + mr + r] = acc0[r];
        #pragma unroll
        for (int r = 0; r < 4; ++r) olds[(16 + o) * 65 + mr + r] = acc1[r];
    }
    __syncthreads();
    const int o  = tid >> 3;
    const int m8 = (tid & 7) * 8;
    float* op = out + ((size_t)(n * O_OUT + o)) * SP + sp0 + m8;
    float4 a0s = make_float4(olds[o * 65 + m8],     olds[o * 65 + m8 + 1],
                             olds[o * 65 + m8 + 2], olds[o * 65 + m8 + 3]);
    float4 a1s = make_float4(olds[o * 65 + m8 + 4], olds[o * 65 + m8 + 5],
                             olds[o * 65 + m8 + 6], olds[o * 65 + m8 + 7]);
    *(float4*)op       = a0s;
    *(float4*)(op + 4) = a1s;
}

// -----------------------------------------------------------------------------
extern "C" void kernel_launch(void* const* d_in, const int* in_sizes, int n_in,
                              void* d_out, int out_size, void* d_ws, size_t ws_size,
                              hipStream_t stream) {
    (void)in_sizes; (void)n_in; (void)out_size; (void)ws_size;
    const float* x      = (const float*)d_in[0];
    const float* weight = (const float*)d_in[1];
    const float* ow     = (const float*)d_in[2];
    const float* ob     = (const float*)d_in[3];
    float* out = (float*)d_out;

    unsigned short* offs_b = (unsigned short*)d_ws;            // 2*81*SP bf16 = 35.8MB
    unsigned short* xT     = offs_b + (size_t)2 * 81 * SP;     // 2*SP*16 bf16 = 7.1MB
    unsigned short* Bf     = xT + (size_t)2 * SP * 16;         // 43008 bf16
    unsigned short* Wf     = Bf + 43008;                       // 14336 bf16

    prep_xT<<<864, 256, 0, stream>>>(x, xT);
    prep_bfrag<<<168, 256, 0, stream>>>(ow, Bf);
    prep_wfrag<<<56, 256, 0, stream>>>(weight, Wf);
    offs_conv_mfma<<<3456, 256, 0, stream>>>(xT, Bf, ob, offs_b);
    deform_mfma<<<3456, 256, 0, stream>>>(xT, Wf, offs_b, out);
}